// Round 3
// baseline (238.114 us; speedup 1.0000x reference)
//
#include <hip/hip_runtime.h>
#include <hip/hip_bf16.h>

#define B_   8
#define N_   2048
#define FIN  128
#define OUTD 256
#define H_   4
#define LOG2E 1.44269504088896340736f

typedef __bf16 bf16x8 __attribute__((ext_vector_type(8)));
typedef float  f32x4  __attribute__((ext_vector_type(4)));

__device__ inline __bf16 cvt1(float f) {
    __hip_bfloat16 b = __float2bfloat16(f);   // RNE
    return *reinterpret_cast<__bf16*>(&b);
}

// ---------------- kernel 1: fused convert + GEMM + s/t logits ----------------
// grid 1024 (one 16-row panel of the flattened (B*N) rows), block 256 = 4 waves.
// Wave w computes head h=w's 16x64 slice: 4 column-tiles x (K=128 = 4 x MFMA k32).
__global__ __launch_bounds__(256) void gemm_st(const float* __restrict__ X,
                                               const float* __restrict__ W,
                                               const float* __restrict__ a_src,
                                               const float* __restrict__ a_dst,
                                               float* __restrict__ Xt,
                                               float* __restrict__ s_arr,
                                               float* __restrict__ t_arr) {
    int r0   = blockIdx.x * 16;                 // row panel
    int h    = threadIdx.x >> 6;                // wave index == head index
    int lane = threadIdx.x & 63;
    int m = lane & 15, q = lane >> 4;

    const float* Arow = X + (size_t)(r0 + m) * FIN + q * 8;
    f32x4 acc[4] = {{0,0,0,0},{0,0,0,0},{0,0,0,0},{0,0,0,0}};

#pragma unroll
    for (int kc = 0; kc < 4; ++kc) {            // K = 128 = 4 x 32
        float4 alo = *(const float4*)(Arow + kc * 32);
        float4 ahi = *(const float4*)(Arow + kc * 32 + 4);
        bf16x8 af;
        af[0] = cvt1(alo.x); af[1] = cvt1(alo.y); af[2] = cvt1(alo.z); af[3] = cvt1(alo.w);
        af[4] = cvt1(ahi.x); af[5] = cvt1(ahi.y); af[6] = cvt1(ahi.z); af[7] = cvt1(ahi.w);
#pragma unroll
        for (int ct = 0; ct < 4; ++ct) {        // 4 column tiles = 64 channels = head h
            const float* Wrow = W + (size_t)(h * 64 + ct * 16 + m) * FIN + q * 8 + kc * 32;
            float4 blo = *(const float4*)(Wrow);
            float4 bhi = *(const float4*)(Wrow + 4);
            bf16x8 bf;
            bf[0] = cvt1(blo.x); bf[1] = cvt1(blo.y); bf[2] = cvt1(blo.z); bf[3] = cvt1(blo.w);
            bf[4] = cvt1(bhi.x); bf[5] = cvt1(bhi.y); bf[6] = cvt1(bhi.z); bf[7] = cvt1(bhi.w);
            acc[ct] = __builtin_amdgcn_mfma_f32_16x16x32_bf16(af, bf, acc[ct], 0, 0, 0);
        }
    }

    // write Xt: acc[ct] element (row = q*4+reg, col = h*64 + ct*16 + m)
#pragma unroll
    for (int ct = 0; ct < 4; ++ct) {
        float* outp = Xt + (size_t)(r0 + q * 4) * OUTD + h * 64 + ct * 16 + m;
#pragma unroll
        for (int reg = 0; reg < 4; ++reg)
            outp[(size_t)reg * OUTD] = acc[ct][reg];
    }

    // s/t logits for head h, rows r0 + q*4 + reg (pre-scaled by log2 e)
    float sp[4] = {0, 0, 0, 0}, tp[4] = {0, 0, 0, 0};
#pragma unroll
    for (int ct = 0; ct < 4; ++ct) {
        float as = a_src[h * 64 + ct * 16 + m];
        float ad = a_dst[h * 64 + ct * 16 + m];
#pragma unroll
        for (int reg = 0; reg < 4; ++reg) {
            sp[reg] = fmaf(acc[ct][reg], as, sp[reg]);
            tp[reg] = fmaf(acc[ct][reg], ad, tp[reg]);
        }
    }
#pragma unroll
    for (int off = 1; off < 16; off <<= 1) {
#pragma unroll
        for (int reg = 0; reg < 4; ++reg) {
            sp[reg] += __shfl_xor(sp[reg], off);
            tp[reg] += __shfl_xor(tp[reg], off);
        }
    }
    if (m == 0) {
#pragma unroll
        for (int reg = 0; reg < 4; ++reg) {
            size_t row = (size_t)(r0 + q * 4 + reg);
            s_arr[row * H_ + h] = sp[reg] * LOG2E;
            t_arr[row * H_ + h] = tp[reg] * LOG2E;
        }
    }
}

// ---------------- kernel 2: masked-softmax diagonal + output scale ----------------
// grid 1024 (= 8 b * 128 row-tiles), block 256. 16 rows/block, 16 lanes per row.
// NO LDS, NO barriers: the 32 KB t-table per graph is L1/L2-resident (Common-
// mistake #7 — don't stage what cache-fits). The old LDS path had an 8-way bank
// conflict on every t read (lanes stride 64B -> 2 banks per 16-lane group) and
// capped occupancy at 4 blocks/CU; this version runs 8 blocks/CU.
// xor-butterfly reduce gives ALL 16 lanes the row sum -> every lane computes
// diag itself (no diag_lds, no broadcast barrier).
__global__ __launch_bounds__(256, 8) void gat_main(const float* __restrict__ A,
                                                   const float* __restrict__ s_arr,
                                                   const float* __restrict__ t_arr,
                                                   float* __restrict__ out) {
    int b   = blockIdx.x >> 7;
    int rt  = blockIdx.x & 127;
    int tid = threadIdx.x;
    int r   = tid >> 4;          // 0..15 row within tile
    int lj  = tid & 15;          // 16 lanes sweep j
    int gi  = rt * 16 + r;       // row index within graph b

    const f32x4* __restrict__ trow = (const f32x4*)(t_arr + (size_t)b * N_ * H_);
    f32x4 s4 = *(const f32x4*)(s_arr + ((size_t)b * N_ + gi) * H_);
    const float* __restrict__ Arow = A + ((size_t)b * N_ + gi) * N_;

    f32x4 acc = {0.f, 0.f, 0.f, 0.f};

    auto body = [&](float4 a4, int it) {
        int j = it * 64 + lj * 4;
#pragma unroll
        for (int jj = 0; jj < 4; ++jj) {
            f32x4 t4 = trow[j + jj];
            float aj = (jj == 0) ? a4.x : (jj == 1) ? a4.y : (jj == 2) ? a4.z : a4.w;
#pragma unroll
            for (int hh = 0; hh < H_; ++hh) {
                float y = s4[hh] + t4[hh];
                y = fmaxf(y, 0.2f * y);                      // leaky_relu (pre-scaled by log2e)
                acc[hh] = fmaf(aj, __builtin_amdgcn_exp2f(y), acc[hh]);
            }
        }
    };

    // 2-deep software pipeline on the A stream (HBM-critical path)
    float4 a0 = *(const float4*)(Arow + lj * 4);
    float4 a1 = *(const float4*)(Arow + 64 + lj * 4);
    for (int it = 0; it < 30; ++it) {
        float4 an = *(const float4*)(Arow + (it + 2) * 64 + lj * 4);
        body(a0, it);
        a0 = a1; a1 = an;
    }
    body(a0, 30);
    body(a1, 31);

    // xor-butterfly: all 16 lanes of the row end with the full sum
#pragma unroll
    for (int mk = 8; mk > 0; mk >>= 1) {
        acc[0] += __shfl_xor(acc[0], mk);
        acc[1] += __shfl_xor(acc[1], mk);
        acc[2] += __shfl_xor(acc[2], mk);
        acc[3] += __shfl_xor(acc[3], mk);
    }

    // per-lane diag (t[gi] is L1-hot)
    f32x4 ti = trow[gi];
    f32x4 dg;
#pragma unroll
    for (int hh = 0; hh < H_; ++hh) {
        float y = s4[hh] + ti[hh];
        y = fmaxf(y, 0.2f * y);
        dg[hh] = __builtin_amdgcn_exp2f(y) / acc[hh];
    }

    // epilogue: out = diag * X_trans (in place; X_trans lives in d_out)
    float* orow = out + ((size_t)b * N_ + gi) * OUTD;
#pragma unroll
    for (int ii = 0; ii < 4; ++ii) {
        int c = lj * 4 + ii * 64;               // head h == ii (lj*4 < 64)
        float4 v = *(float4*)(orow + c);
        float d = dg[ii];
        v.x *= d; v.y *= d; v.z *= d; v.w *= d;
        *(float4*)(orow + c) = v;
    }
}

extern "C" void kernel_launch(void* const* d_in, const int* in_sizes, int n_in,
                              void* d_out, int out_size, void* d_ws, size_t ws_size,
                              hipStream_t stream) {
    const float* A     = (const float*)d_in[0];
    const float* X     = (const float*)d_in[1];
    const float* W     = (const float*)d_in[2];
    const float* a_src = (const float*)d_in[3];
    const float* a_dst = (const float*)d_in[4];
    float* out = (float*)d_out;

    // workspace carve-up (s/t logits only)
    char* ws = (char*)d_ws;
    float* s_arr = (float*)ws;                                //   262,144 B
    float* t_arr = (float*)(ws + 262144);                     //   262,144 B

    // 1) fused: convert + X@W.T (into d_out) + s/t logits
    gemm_st<<<1024, 256, 0, stream>>>(X, W, a_src, a_dst, out, s_arr, t_arr);
    // 2) masked softmax diagonal + scale
    gat_main<<<1024, 256, 0, stream>>>(A, s_arr, t_arr, out);
}